// Round 1
// baseline (3318.484 us; speedup 1.0000x reference)
//
#include <hip/hip_runtime.h>
#include <math.h>

#define N_ROWS 32768
#define KCODES 8192
#define DIM 256
#define BM 64            // rows per block
#define BK 64            // codes per tile
#define NT (KCODES / BK) // 128 tiles
#define STRIDE 260       // LDS row stride in floats (multiple of 4 for b128 alignment)
#define NTHREADS 256

__device__ __forceinline__ float sqf(float x) { return __fmul_rn(x, x); }

// numpy pairwise sum of fl(x_i^2), n=256: two 128-blocks, each 8 accumulators,
// combine ((r0+r1)+(r2+r3))+((r4+r5)+(r6+r7)), then block0+block1. All f32, no FMA.
template <typename LD>
__device__ __forceinline__ float pairwise256_sq(LD ld) {
  float blocks[2];
#pragma unroll
  for (int b = 0; b < 2; ++b) {
    float r[8];
#pragma unroll
    for (int j = 0; j < 8; ++j) r[j] = sqf(ld(b * 128 + j));
#pragma unroll
    for (int i = 8; i < 128; i += 8)
#pragma unroll
      for (int j = 0; j < 8; ++j) r[j] = __fadd_rn(r[j], sqf(ld(b * 128 + i + j)));
    blocks[b] = __fadd_rn(__fadd_rn(__fadd_rn(r[0], r[1]), __fadd_rn(r[2], r[3])),
                          __fadd_rn(__fadd_rn(r[4], r[5]), __fadd_rn(r[6], r[7])));
  }
  return __fadd_rn(blocks[0], blocks[1]);
}

// Per-code ||c||^2 with numpy-pairwise order (bitwise-replicated).
__global__ void vq_cc_kernel(const float* __restrict__ cb, float* __restrict__ cc) {
  int k = blockIdx.x * blockDim.x + threadIdx.x;
  if (k >= KCODES) return;
  const float* row = cb + (size_t)k * DIM;
  cc[k] = pairwise256_sq([&](int i) { return row[i]; });
}

__launch_bounds__(NTHREADS, 1)
__global__ void vq_main_kernel(const float* __restrict__ zg, const float* __restrict__ cb,
                               const float* __restrict__ ccg, float* __restrict__ out,
                               double* __restrict__ loss_acc) {
  __shared__ float z_s[BM * STRIDE];
  __shared__ float c_s[BK * STRIDE];
  __shared__ float zz_s[BM];

  const int tid = threadIdx.x;
  const int tx = tid & 15;   // code group
  const int ty = tid >> 4;   // row group (0..15)
  const int blk = blockIdx.x;
  const float* zrow0 = zg + (size_t)blk * BM * DIM;

  // ---- stage z tile (coalesced: one row per wave per step) ----
#pragma unroll
  for (int p = 0; p < 16; ++p) {
    int i = tid + p * NTHREADS;
    int r = i >> 6, c = i & 63;
    float4 v = *(const float4*)(zrow0 + r * DIM + c * 4);
    *(float4*)&z_s[r * STRIDE + c * 4] = v;
  }
  // ---- stage first codebook tile ----
#pragma unroll
  for (int p = 0; p < 16; ++p) {
    int i = tid + p * NTHREADS;
    int r = i >> 6, c = i & 63;
    float4 v = *(const float4*)(cb + (size_t)r * DIM + c * 4);
    *(float4*)&c_s[r * STRIDE + c * 4] = v;
  }
  __syncthreads();

  // ---- per-row ||z||^2, numpy-pairwise exact ----
  if (tid < BM) {
    const float* zr = &z_s[tid * STRIDE];
    zz_s[tid] = pairwise256_sq([&](int i) { return zr[i]; });
  }
  __syncthreads();

  float zzr[4];
#pragma unroll
  for (int m = 0; m < 4; ++m) zzr[m] = zz_s[ty + 16 * m];

  float bestd[4] = {INFINITY, INFINITY, INFINITY, INFINITY};
  int besti[4] = {0, 0, 0, 0};

  for (int t = 0; t < NT; ++t) {
    // prefetch next codebook tile into registers (hidden under compute)
    float4 pf[16];
    if (t + 1 < NT) {
      const float* cbase = cb + (size_t)(t + 1) * BK * DIM;
#pragma unroll
      for (int p = 0; p < 16; ++p) {
        int i = tid + p * NTHREADS;
        int r = i >> 6, c = i & 63;
        pf[p] = *(const float4*)(cbase + r * DIM + c * 4);
      }
    }

    int k0 = t * BK;
    float ccr[4];
#pragma unroll
    for (int j = 0; j < 4; ++j) ccr[j] = ccg[k0 + tx + 16 * j];

    float acc[4][4] = {};
    for (int db = 0; db < 64; ++db) {
      float4 a[4], b[4];
#pragma unroll
      for (int m = 0; m < 4; ++m) a[m] = *(const float4*)&z_s[(ty + 16 * m) * STRIDE + db * 4];
#pragma unroll
      for (int j = 0; j < 4; ++j) b[j] = *(const float4*)&c_s[(tx + 16 * j) * STRIDE + db * 4];
#pragma unroll
      for (int m = 0; m < 4; ++m)
#pragma unroll
        for (int j = 0; j < 4; ++j) {
          acc[m][j] = fmaf(a[m].x, b[j].x, acc[m][j]);
          acc[m][j] = fmaf(a[m].y, b[j].y, acc[m][j]);
          acc[m][j] = fmaf(a[m].z, b[j].z, acc[m][j]);
          acc[m][j] = fmaf(a[m].w, b[j].w, acc[m][j]);
        }
    }

    // d = fl(fl(zz+cc) - 2*dot); strict < keeps first (lowest k) on ties,
    // since k ascends across j and across tiles.
#pragma unroll
    for (int m = 0; m < 4; ++m)
#pragma unroll
      for (int j = 0; j < 4; ++j) {
        float d = __fsub_rn(__fadd_rn(zzr[m], ccr[j]), 2.0f * acc[m][j]);
        if (d < bestd[m]) { bestd[m] = d; besti[m] = k0 + tx + 16 * j; }
      }

    __syncthreads();
    if (t + 1 < NT) {
#pragma unroll
      for (int p = 0; p < 16; ++p) {
        int i = tid + p * NTHREADS;
        int r = i >> 6, c = i & 63;
        *(float4*)&c_s[r * STRIDE + c * 4] = pf[p];
      }
    }
    __syncthreads();
  }

  // ---- epilogue: reduce (d, idx) lex-min over the 16 tx-lanes of each ty group ----
  double lsum = 0.0;
#pragma unroll
  for (int m = 0; m < 4; ++m) {
    float d = bestd[m];
    int idx = besti[m];
#pragma unroll
    for (int off = 8; off >= 1; off >>= 1) {
      float od = __shfl_xor(d, off, 16);
      int oi = __shfl_xor(idx, off, 16);
      if (od < d || (od == d && oi < idx)) { d = od; idx = oi; }
    }
    int rlocal = ty + 16 * m;
    size_t R = (size_t)blk * BM + rlocal;
    if (tx == 0) out[(size_t)N_ROWS * DIM + 1 + R] = (float)idx;

    const float4* q4 = (const float4*)(cb + (size_t)idx * DIM);
    float* orow = out + R * DIM;
#pragma unroll
    for (int c2 = 0; c2 < 4; ++c2) {
      int dbase = tx * 16 + c2 * 4;
      float4 q = q4[tx * 4 + c2];
      float4 zv = *(const float4*)&z_s[rlocal * STRIDE + dbase];
      float dx = __fsub_rn(q.x, zv.x), dy = __fsub_rn(q.y, zv.y);
      float dz = __fsub_rn(q.z, zv.z), dw = __fsub_rn(q.w, zv.w);
      float4 o;
      o.x = __fadd_rn(zv.x, dx); o.y = __fadd_rn(zv.y, dy);
      o.z = __fadd_rn(zv.z, dz); o.w = __fadd_rn(zv.w, dw);
      *(float4*)(orow + dbase) = o;
      lsum += (double)__fmul_rn(dx, dx) + (double)__fmul_rn(dy, dy) +
              (double)__fmul_rn(dz, dz) + (double)__fmul_rn(dw, dw);
    }
  }

  // wave-reduce f64 partial, one atomic per wave
#pragma unroll
  for (int off = 32; off >= 1; off >>= 1) lsum += __shfl_xor(lsum, off, 64);
  if ((tid & 63) == 0) atomicAdd(loss_acc, lsum);
}

__global__ void vq_finalize_kernel(const double* __restrict__ loss_acc, float* __restrict__ out) {
  double m = *loss_acc / (double)((size_t)N_ROWS * DIM);
  float mf = (float)m;
  out[(size_t)N_ROWS * DIM] = __fadd_rn(mf, __fmul_rn(0.25f, mf));
}

extern "C" void kernel_launch(void* const* d_in, const int* in_sizes, int n_in,
                              void* d_out, int out_size, void* d_ws, size_t ws_size,
                              hipStream_t stream) {
  const float* z = (const float*)d_in[0];
  const float* cb = (const float*)d_in[1];
  float* out = (float*)d_out;
  double* lacc = (double*)d_ws;
  float* cc = (float*)((char*)d_ws + 16);

  hipMemsetAsync(d_ws, 0, 16, stream);
  hipLaunchKernelGGL(vq_cc_kernel, dim3(KCODES / 256), dim3(256), 0, stream, cb, cc);
  hipLaunchKernelGGL(vq_main_kernel, dim3(N_ROWS / BM), dim3(NTHREADS), 0, stream,
                     z, cb, cc, out, lacc);
  hipLaunchKernelGGL(vq_finalize_kernel, dim3(1), dim3(1), 0, stream, lacc, out);
}

// Round 3
// 724.907 us; speedup vs baseline: 4.5778x; 4.5778x over previous
//
#include <hip/hip_runtime.h>
#include <math.h>

#define N_ROWS 32768
#define KCODES 8192
#define DIM 256
#define NZ (N_ROWS * DIM)      // z_q elements
#define TILE_K 64              // codes per screen tile
#define NTILES (KCODES / TILE_K)
#define CAND_CAP 16
#define W_PRUNE 2e-4f

typedef __attribute__((ext_vector_type(8))) short short8v;
typedef __attribute__((ext_vector_type(4))) float float4v;

__device__ __forceinline__ float sqf(float x) { return __fmul_rn(x, x); }

__device__ __forceinline__ unsigned short f2bf(float f) {
  unsigned u = __float_as_uint(f);
  return (unsigned short)((u + 0x7fffu + ((u >> 16) & 1u)) >> 16);
}

// numpy pairwise sum of fl(x_i^2), n=256 (bitwise-replicated; verified round 1).
template <typename LD>
__device__ __forceinline__ float pairwise256_sq(LD ld) {
  float blocks[2];
#pragma unroll
  for (int b = 0; b < 2; ++b) {
    float r[8];
#pragma unroll
    for (int j = 0; j < 8; ++j) r[j] = sqf(ld(b * 128 + j));
    for (int i = 8; i < 128; i += 8)
#pragma unroll
      for (int j = 0; j < 8; ++j) r[j] = __fadd_rn(r[j], sqf(ld(b * 128 + i + j)));
    blocks[b] = __fadd_rn(__fadd_rn(__fadd_rn(r[0], r[1]), __fadd_rn(r[2], r[3])),
                          __fadd_rn(__fadd_rn(r[4], r[5]), __fadd_rn(r[6], r[7])));
  }
  return __fadd_rn(blocks[0], blocks[1]);
}

// branchless top-3 insert (descending); stable for equal scores (old stays above)
__device__ __forceinline__ void ins3(float (&s)[3], int (&ix)[3], float sc, int id) {
  bool a0 = sc > s[0], a1 = sc > s[1], a2 = sc > s[2];
  float n0 = a0 ? sc : s[0];
  int   m0 = a0 ? id : ix[0];
  float n1 = a0 ? s[0] : (a1 ? sc : s[1]);
  int   m1 = a0 ? ix[0] : (a1 ? id : ix[1]);
  float n2 = a1 ? s[1] : (a2 ? sc : s[2]);
  int   m2 = a1 ? ix[1] : (a2 ? id : ix[2]);
  s[0] = n0; s[1] = n1; s[2] = n2; ix[0] = m0; ix[1] = m1; ix[2] = m2;
}

// ---- codebook f32 -> bf16 convert (coalesced, 8 elems/thread) ----
__global__ void vq_conv(const float* __restrict__ cb, short* __restrict__ chi) {
  int i = blockIdx.x * blockDim.x + threadIdx.x;
  const float* p = cb + (size_t)i * 8;
  float4v f0 = *(const float4v*)p;
  float4v f1 = *(const float4v*)(p + 4);
  short8v v;
  v[0] = (short)f2bf(f0[0]); v[1] = (short)f2bf(f0[1]);
  v[2] = (short)f2bf(f0[2]); v[3] = (short)f2bf(f0[3]);
  v[4] = (short)f2bf(f1[0]); v[5] = (short)f2bf(f1[1]);
  v[6] = (short)f2bf(f1[2]); v[7] = (short)f2bf(f1[3]);
  *(short8v*)(chi + (size_t)i * 8) = v;
}

// ---- MFMA screen: per-row top-candidate collection ----
// 512 blocks x 256 thr. Block = 64 rows. Wave w: rowgroup rg=w>>1 (32 rows,
// 2 frags), codegroup cg=w&1 (frags 2cg,2cg+1 of each 64-code tile).
__launch_bounds__(256, 2)
__global__ void vq_screen(const float* __restrict__ z, const short* __restrict__ chi,
                          int* __restrict__ cnt, unsigned short* __restrict__ cand) {
  __shared__ __align__(16) short cs[2][TILE_K * DIM];  // 2 x 32 KB

  const int tid = threadIdx.x;
  const int w = tid >> 6, l = tid & 63;
  const int rg = w >> 1, cg = w & 1;
  const int R0 = blockIdx.x * 64;

  // ---- A fragments in registers: rows R0 + rg*32 + h*16 + (l&15), k-octet (l>>4)*8 ----
  short8v a[2][8];
  {
    const int rql = l & 15, kg = (l >> 4) * 8;
#pragma unroll
    for (int h = 0; h < 2; ++h) {
      const float* zr = z + (size_t)(R0 + rg * 32 + h * 16 + rql) * DIM + kg;
#pragma unroll
      for (int s = 0; s < 8; ++s) {
        const float* p = zr + s * 32;
        float4v f0 = *(const float4v*)p;
        float4v f1 = *(const float4v*)(p + 4);
        short8v v;
        v[0] = (short)f2bf(f0[0]); v[1] = (short)f2bf(f0[1]);
        v[2] = (short)f2bf(f0[2]); v[3] = (short)f2bf(f0[3]);
        v[4] = (short)f2bf(f1[0]); v[5] = (short)f2bf(f1[1]);
        v[6] = (short)f2bf(f1[2]); v[7] = (short)f2bf(f1[3]);
        a[h][s] = v;
      }
    }
  }

  float t3s[8][3];
  int t3i[8][3];
#pragma unroll
  for (int s = 0; s < 8; ++s)
#pragma unroll
    for (int q = 0; q < 3; ++q) { t3s[s][q] = -INFINITY; t3i[s][q] = 0; }

  // stage: linear LDS dest (wave-uniform base + lane*16), XOR-preswizzled global src
  auto stage = [&](int t, int bufi) {
    const char* tb = (const char*)chi + (size_t)t * TILE_K * DIM * 2;
#pragma unroll
    for (int p = 0; p < 8; ++p) {
      int i = p * 256 + w * 64 + l;
      int row = i >> 5, c = i & 31;
      const char* g = tb + (size_t)(((row << 5) + (c ^ (row & 7))) << 4);
      short* dst = (short*)cs[bufi] + (size_t)(p * 256 + w * 64) * 8;
      __builtin_amdgcn_global_load_lds(
          (const __attribute__((address_space(1))) unsigned int*)g,
          (__attribute__((address_space(3))) unsigned int*)dst, 16, 0, 0);
    }
  };

  stage(0, 0);
  __syncthreads();

  for (int t = 0; t < NTILES; ++t) {
    int cur = t & 1;
    if (t + 1 < NTILES) stage(t + 1, cur ^ 1);

    const char* base = (const char*)cs[cur];
#pragma unroll
    for (int cf = 0; cf < 2; ++cf) {
      const int f = cg * 2 + cf;
      const int row = f * 16 + (l & 15);
      const int sw = (row & 7) << 4;
      short8v b[8];
#pragma unroll
      for (int s = 0; s < 8; ++s) {
        int koff = s * 64 + ((l >> 4) << 4);
        b[s] = *(const short8v*)(base + ((size_t)row << 9) + (koff ^ sw));
      }
      float4v acc0 = {0.f, 0.f, 0.f, 0.f}, acc1 = {0.f, 0.f, 0.f, 0.f};
#pragma unroll
      for (int s = 0; s < 8; ++s) {
        acc0 = __builtin_amdgcn_mfma_f32_16x16x32_bf16(a[0][s], b[s], acc0, 0, 0, 0);
        acc1 = __builtin_amdgcn_mfma_f32_16x16x32_bf16(a[1][s], b[s], acc1, 0, 0, 0);
      }
      const int code = t * 64 + f * 16 + (l & 15);
#pragma unroll
      for (int reg = 0; reg < 4; ++reg) {
        ins3(t3s[reg], t3i[reg], acc0[reg], code);         // h=0 rows
        ins3(t3s[4 + reg], t3i[4 + reg], acc1[reg], code); // h=1 rows
      }
    }
    __syncthreads();
  }

  // ---- epilogue: cross-wave row max, prune, emit candidates ----
  float* smaxbuf = (float*)cs[0];  // [64 rows][2 cg]
#pragma unroll
  for (int slot = 0; slot < 8; ++slot) {
    float m = t3s[slot][0];
    m = fmaxf(m, __shfl_xor(m, 1, 16));
    m = fmaxf(m, __shfl_xor(m, 2, 16));
    m = fmaxf(m, __shfl_xor(m, 4, 16));
    m = fmaxf(m, __shfl_xor(m, 8, 16));
    int rr = rg * 32 + (slot >> 2) * 16 + ((l >> 4) << 2) + (slot & 3);
    if ((l & 15) == 0) smaxbuf[rr * 2 + cg] = m;
  }
  __syncthreads();
#pragma unroll
  for (int slot = 0; slot < 8; ++slot) {
    int rr = rg * 32 + (slot >> 2) * 16 + ((l >> 4) << 2) + (slot & 3);
    float gmax = fmaxf(smaxbuf[rr * 2], smaxbuf[rr * 2 + 1]);
    float thr = gmax - W_PRUNE;
    int Rg = R0 + rr;
#pragma unroll
    for (int q = 0; q < 3; ++q) {
      if (t3s[slot][q] >= thr) {
        int pos = atomicAdd(&cnt[Rg], 1);
        if (pos < CAND_CAP) cand[Rg * CAND_CAP + pos] = (unsigned short)t3i[slot][q];
      }
    }
  }
}

// ---- exact f32 recheck + outputs (wave per row) ----
__launch_bounds__(256)
__global__ void vq_recheck(const float* __restrict__ z, const float* __restrict__ cb,
                           const int* __restrict__ cnt, const unsigned short* __restrict__ cand,
                           float* __restrict__ out, double* __restrict__ lacc) {
  __shared__ float zs[4][DIM];
  const int w = threadIdx.x >> 6, l = threadIdx.x & 63;
  const size_t R = (size_t)blockIdx.x * 4 + w;

  *(float4v*)&zs[w][l * 4] = *(const float4v*)(z + R * DIM + l * 4);
  __syncthreads();

  // exact ||z||^2: 16 lanes do the 8-acc pairwise partials, exact combine tree
  float r = 0.f;
  if (l < 16) {
    const int b = l >> 3, j = l & 7;
    const float* zr = zs[w];
    r = sqf(zr[b * 128 + j]);
    for (int i = 8; i < 128; i += 8) r = __fadd_rn(r, sqf(zr[b * 128 + i + j]));
  }
  float rr[16];
#pragma unroll
  for (int j = 0; j < 16; ++j) rr[j] = __shfl(r, j, 64);
  float b0 = __fadd_rn(__fadd_rn(__fadd_rn(rr[0], rr[1]), __fadd_rn(rr[2], rr[3])),
                       __fadd_rn(__fadd_rn(rr[4], rr[5]), __fadd_rn(rr[6], rr[7])));
  float b1 = __fadd_rn(__fadd_rn(__fadd_rn(rr[8], rr[9]), __fadd_rn(rr[10], rr[11])),
                       __fadd_rn(__fadd_rn(rr[12], rr[13]), __fadd_rn(rr[14], rr[15])));
  float zz = __fadd_rn(b0, b1);

  int nc = cnt[R];
  float d = INFINITY;
  int idx = 0x7fffffff;
  if (nc > CAND_CAP) {
    // overflow fallback: full exact scan, lane-strided (ascending codes per lane,
    // strict < keeps lowest index; cross-lane lex-min below)
    for (int c0 = l; c0 < KCODES; c0 += 64) {
      const float* cr = cb + (size_t)c0 * DIM;
      float cc = pairwise256_sq([&](int i) { return cr[i]; });
      float acc = 0.f;
      for (int k = 0; k < DIM; ++k) acc = fmaf(zs[w][k], cr[k], acc);
      float dd = __fsub_rn(__fadd_rn(zz, cc), 2.0f * acc);
      if (dd < d) { d = dd; idx = c0; }
    }
  } else if (l < nc) {
    int ci = cand[R * CAND_CAP + l];
    const float* cr = cb + (size_t)ci * DIM;
    float cc = pairwise256_sq([&](int i) { return cr[i]; });
    float acc = 0.f;
    for (int k = 0; k < DIM; ++k) acc = fmaf(zs[w][k], cr[k], acc);
    d = __fsub_rn(__fadd_rn(zz, cc), 2.0f * acc);
    idx = ci;
  }
  // lex-min (d, idx) across wave
#pragma unroll
  for (int off = 32; off; off >>= 1) {
    float od = __shfl_xor(d, off, 64);
    int oi = __shfl_xor(idx, off, 64);
    if (od < d || (od == d && oi < idx)) { d = od; idx = oi; }
  }

  if (l == 0) out[(size_t)NZ + 1 + R] = (float)idx;

  const float* cw = cb + (size_t)idx * DIM;
  float4v q = *(const float4v*)(cw + l * 4);
  float4v zv = *(const float4v*)&zs[w][l * 4];
  double lsum = 0.0;
  float4v o;
#pragma unroll
  for (int c = 0; c < 4; ++c) {
    float dq = __fsub_rn(q[c], zv[c]);
    o[c] = __fadd_rn(zv[c], dq);
    lsum += (double)__fmul_rn(dq, dq);
  }
  *(float4v*)(out + R * DIM + l * 4) = o;

#pragma unroll
  for (int off = 32; off; off >>= 1) lsum += __shfl_xor(lsum, off, 64);
  if (l == 0) atomicAdd(lacc, lsum);
}

__global__ void vq_finalize(const double* __restrict__ lacc, float* __restrict__ out) {
  double m = *lacc / (double)((size_t)N_ROWS * DIM);
  float mf = (float)m;
  out[NZ] = __fadd_rn(mf, __fmul_rn(0.25f, mf));
}

extern "C" void kernel_launch(void* const* d_in, const int* in_sizes, int n_in,
                              void* d_out, int out_size, void* d_ws, size_t ws_size,
                              hipStream_t stream) {
  const float* z = (const float*)d_in[0];
  const float* cb = (const float*)d_in[1];
  float* out = (float*)d_out;

  double* lacc = (double*)d_ws;
  int* cnt = (int*)((char*)d_ws + 256);
  unsigned short* cand = (unsigned short*)((char*)d_ws + 256 + N_ROWS * 4);
  short* chi = (short*)((char*)d_ws + (2u << 20));

  hipMemsetAsync(d_ws, 0, 256 + N_ROWS * 4, stream);
  hipLaunchKernelGGL(vq_conv, dim3(KCODES * DIM / 8 / 256), dim3(256), 0, stream, cb, chi);
  hipLaunchKernelGGL(vq_screen, dim3(N_ROWS / 64), dim3(256), 0, stream, z, chi, cnt, cand);
  hipLaunchKernelGGL(vq_recheck, dim3(N_ROWS / 4), dim3(256), 0, stream, z, cb, cnt, cand, out, lacc);
  hipLaunchKernelGGL(vq_finalize, dim3(1), dim3(1), 0, stream, lacc, out);
}

// Round 4
// 361.256 us; speedup vs baseline: 9.1860x; 2.0066x over previous
//
#include <hip/hip_runtime.h>
#include <math.h>

#define N_ROWS 32768
#define KCODES 8192
#define DIM 256
#define NZ (N_ROWS * DIM)      // z_q elements
#define TILE_K 64              // codes per screen tile
#define NTILES (KCODES / TILE_K)
#define CAND_CAP 16
#define W_PRUNE 2e-4f

typedef __attribute__((ext_vector_type(8))) short short8v;
typedef __attribute__((ext_vector_type(4))) float float4v;

__device__ __forceinline__ float sqf(float x) { return __fmul_rn(x, x); }

__device__ __forceinline__ unsigned short f2bf(float f) {
  unsigned u = __float_as_uint(f);
  return (unsigned short)((u + 0x7fffu + ((u >> 16) & 1u)) >> 16);
}

// numpy pairwise sum of fl(x_i^2), n=256 (bitwise-replicated; verified rounds 1/3).
template <typename LD>
__device__ __forceinline__ float pairwise256_sq(LD ld) {
  float blocks[2];
#pragma unroll
  for (int b = 0; b < 2; ++b) {
    float r[8];
#pragma unroll
    for (int j = 0; j < 8; ++j) r[j] = sqf(ld(b * 128 + j));
    for (int i = 8; i < 128; i += 8)
#pragma unroll
      for (int j = 0; j < 8; ++j) r[j] = __fadd_rn(r[j], sqf(ld(b * 128 + i + j)));
    blocks[b] = __fadd_rn(__fadd_rn(__fadd_rn(r[0], r[1]), __fadd_rn(r[2], r[3])),
                          __fadd_rn(__fadd_rn(r[4], r[5]), __fadd_rn(r[6], r[7])));
  }
  return __fadd_rn(blocks[0], blocks[1]);
}

// branchless top-3 insert (descending); stable for equal scores
__device__ __forceinline__ void ins3(float (&s)[3], int (&ix)[3], float sc, int id) {
  bool a0 = sc > s[0], a1 = sc > s[1], a2 = sc > s[2];
  float n0 = a0 ? sc : s[0];
  int   m0 = a0 ? id : ix[0];
  float n1 = a0 ? s[0] : (a1 ? sc : s[1]);
  int   m1 = a0 ? ix[0] : (a1 ? id : ix[1]);
  float n2 = a1 ? s[1] : (a2 ? sc : s[2]);
  int   m2 = a1 ? ix[1] : (a2 ? id : ix[2]);
  s[0] = n0; s[1] = n1; s[2] = n2; ix[0] = m0; ix[1] = m1; ix[2] = m2;
}

// ---- codebook f32 -> bf16 convert ----
__global__ void vq_conv(const float* __restrict__ cb, short* __restrict__ chi) {
  int i = blockIdx.x * blockDim.x + threadIdx.x;
  const float* p = cb + (size_t)i * 8;
  float4v f0 = *(const float4v*)p;
  float4v f1 = *(const float4v*)(p + 4);
  short8v v;
  v[0] = (short)f2bf(f0[0]); v[1] = (short)f2bf(f0[1]);
  v[2] = (short)f2bf(f0[2]); v[3] = (short)f2bf(f0[3]);
  v[4] = (short)f2bf(f1[0]); v[5] = (short)f2bf(f1[1]);
  v[6] = (short)f2bf(f1[2]); v[7] = (short)f2bf(f1[3]);
  *(short8v*)(chi + (size_t)i * 8) = v;
}

// ---- MFMA screen (unchanged from round 3, verified) ----
__launch_bounds__(256, 2)
__global__ void vq_screen(const float* __restrict__ z, const short* __restrict__ chi,
                          int* __restrict__ cnt, unsigned short* __restrict__ cand) {
  __shared__ __align__(16) short cs[2][TILE_K * DIM];  // 2 x 32 KB

  const int tid = threadIdx.x;
  const int w = tid >> 6, l = tid & 63;
  const int rg = w >> 1, cg = w & 1;
  const int R0 = blockIdx.x * 64;

  short8v a[2][8];
  {
    const int rql = l & 15, kg = (l >> 4) * 8;
#pragma unroll
    for (int h = 0; h < 2; ++h) {
      const float* zr = z + (size_t)(R0 + rg * 32 + h * 16 + rql) * DIM + kg;
#pragma unroll
      for (int s = 0; s < 8; ++s) {
        const float* p = zr + s * 32;
        float4v f0 = *(const float4v*)p;
        float4v f1 = *(const float4v*)(p + 4);
        short8v v;
        v[0] = (short)f2bf(f0[0]); v[1] = (short)f2bf(f0[1]);
        v[2] = (short)f2bf(f0[2]); v[3] = (short)f2bf(f0[3]);
        v[4] = (short)f2bf(f1[0]); v[5] = (short)f2bf(f1[1]);
        v[6] = (short)f2bf(f1[2]); v[7] = (short)f2bf(f1[3]);
        a[h][s] = v;
      }
    }
  }

  float t3s[8][3];
  int t3i[8][3];
#pragma unroll
  for (int s = 0; s < 8; ++s)
#pragma unroll
    for (int q = 0; q < 3; ++q) { t3s[s][q] = -INFINITY; t3i[s][q] = 0; }

  auto stage = [&](int t, int bufi) {
    const char* tb = (const char*)chi + (size_t)t * TILE_K * DIM * 2;
#pragma unroll
    for (int p = 0; p < 8; ++p) {
      int i = p * 256 + w * 64 + l;
      int row = i >> 5, c = i & 31;
      const char* g = tb + (size_t)(((row << 5) + (c ^ (row & 7))) << 4);
      short* dst = (short*)cs[bufi] + (size_t)(p * 256 + w * 64) * 8;
      __builtin_amdgcn_global_load_lds(
          (const __attribute__((address_space(1))) unsigned int*)g,
          (__attribute__((address_space(3))) unsigned int*)dst, 16, 0, 0);
    }
  };

  stage(0, 0);
  __syncthreads();

  for (int t = 0; t < NTILES; ++t) {
    int cur = t & 1;
    if (t + 1 < NTILES) stage(t + 1, cur ^ 1);

    const char* base = (const char*)cs[cur];
#pragma unroll
    for (int cf = 0; cf < 2; ++cf) {
      const int f = cg * 2 + cf;
      const int row = f * 16 + (l & 15);
      const int sw = (row & 7) << 4;
      short8v b[8];
#pragma unroll
      for (int s = 0; s < 8; ++s) {
        int koff = s * 64 + ((l >> 4) << 4);
        b[s] = *(const short8v*)(base + ((size_t)row << 9) + (koff ^ sw));
      }
      float4v acc0 = {0.f, 0.f, 0.f, 0.f}, acc1 = {0.f, 0.f, 0.f, 0.f};
#pragma unroll
      for (int s = 0; s < 8; ++s) {
        acc0 = __builtin_amdgcn_mfma_f32_16x16x32_bf16(a[0][s], b[s], acc0, 0, 0, 0);
        acc1 = __builtin_amdgcn_mfma_f32_16x16x32_bf16(a[1][s], b[s], acc1, 0, 0, 0);
      }
      const int code = t * 64 + f * 16 + (l & 15);
#pragma unroll
      for (int reg = 0; reg < 4; ++reg) {
        ins3(t3s[reg], t3i[reg], acc0[reg], code);
        ins3(t3s[4 + reg], t3i[4 + reg], acc1[reg], code);
      }
    }
    __syncthreads();
  }

  float* smaxbuf = (float*)cs[0];  // [64 rows][2 cg]
#pragma unroll
  for (int slot = 0; slot < 8; ++slot) {
    float m = t3s[slot][0];
    m = fmaxf(m, __shfl_xor(m, 1, 16));
    m = fmaxf(m, __shfl_xor(m, 2, 16));
    m = fmaxf(m, __shfl_xor(m, 4, 16));
    m = fmaxf(m, __shfl_xor(m, 8, 16));
    int rr = rg * 32 + (slot >> 2) * 16 + ((l >> 4) << 2) + (slot & 3);
    if ((l & 15) == 0) smaxbuf[rr * 2 + cg] = m;
  }
  __syncthreads();
#pragma unroll
  for (int slot = 0; slot < 8; ++slot) {
    int rr = rg * 32 + (slot >> 2) * 16 + ((l >> 4) << 2) + (slot & 3);
    float gmax = fmaxf(smaxbuf[rr * 2], smaxbuf[rr * 2 + 1]);
    float thr = gmax - W_PRUNE;
    int Rg = R0 + rr;
#pragma unroll
    for (int q = 0; q < 3; ++q) {
      if (t3s[slot][q] >= thr) {
        int pos = atomicAdd(&cnt[Rg], 1);
        if (pos < CAND_CAP) cand[Rg * CAND_CAP + pos] = (unsigned short)t3i[slot][q];
      }
    }
  }
}

// ---- recheck v2: 4 rows/wave x 16 slots/lane, fused outputs ----
__launch_bounds__(256)
__global__ void vq_recheck2(const float* __restrict__ z, const float* __restrict__ cb,
                            const int* __restrict__ cnt, const unsigned short* __restrict__ cand,
                            float* __restrict__ out, double* __restrict__ lacc) {
  __shared__ __align__(16) float zs[16][260];   // +4 pad: rows 4 banks apart
  __shared__ double lpart[4];
  const int tid = threadIdx.x;
  const int w = tid >> 6, l = tid & 63;
  const int rw = l >> 4, sl = l & 15;  // row-in-wave, candidate slot
  const int lr = w * 4 + rw;           // local row 0..15
  const size_t R0 = (size_t)blockIdx.x * 16;
  const size_t R = R0 + lr;

  // stage 16 z rows (coalesced float4)
#pragma unroll
  for (int it = 0; it < 4; ++it) {
    int flat = it * 1024 + tid * 4;
    int r = flat >> 8, c = flat & 255;
    *(float4v*)&zs[r][c] = *(const float4v*)(z + R0 * DIM + flat);
  }
  __syncthreads();

  // ---- zz per row, bitwise pairwise (verified pattern): 16 lanes/row ----
  float zz;
  {
    const int b = (l >> 3) & 1, j = l & 7;
    const float* zr = zs[lr];
    float r = sqf(zr[b * 128 + j]);
    for (int i = 8; i < 128; i += 8) r = __fadd_rn(r, sqf(zr[b * 128 + i + j]));
    float rr[16];
    const int gbase = l & 48;
#pragma unroll
    for (int j2 = 0; j2 < 16; ++j2) rr[j2] = __shfl(r, gbase + j2, 64);
    float b0 = __fadd_rn(__fadd_rn(__fadd_rn(rr[0], rr[1]), __fadd_rn(rr[2], rr[3])),
                         __fadd_rn(__fadd_rn(rr[4], rr[5]), __fadd_rn(rr[6], rr[7])));
    float b1 = __fadd_rn(__fadd_rn(__fadd_rn(rr[8], rr[9]), __fadd_rn(rr[10], rr[11])),
                         __fadd_rn(__fadd_rn(rr[12], rr[13]), __fadd_rn(rr[14], rr[15])));
    zz = __fadd_rn(b0, b1);
  }

  // exact d for one code (per-lane serial, EXACT round-3 op order)
  auto exact_d = [&](int code) -> float {
    const float* cr = cb + (size_t)code * DIM;
    float cc = pairwise256_sq([&](int i) { return cr[i]; });
    float acc = 0.f;
    const float* zr = zs[lr];
    for (int k = 0; k < DIM; k += 4) {
      float4v zf = *(const float4v*)&zr[k];
      float4v cf = *(const float4v*)&cr[k];
      acc = fmaf(zf[0], cf[0], acc);
      acc = fmaf(zf[1], cf[1], acc);
      acc = fmaf(zf[2], cf[2], acc);
      acc = fmaf(zf[3], cf[3], acc);
    }
    return __fsub_rn(__fadd_rn(zz, cc), 2.0f * acc);
  };

  int nc = cnt[R];
  float d = INFINITY;
  int idx = 0x7fffffff;
  if (nc > CAND_CAP) {
    // overflow fallback: exact full scan, slot-strided ascending
    for (int c0 = sl; c0 < KCODES; c0 += 16) {
      float dd = exact_d(c0);
      if (dd < d) { d = dd; idx = c0; }
    }
  } else if (sl < nc) {
    int ci = cand[R * CAND_CAP + sl];
    d = exact_d(ci);
    idx = ci;
  }
  // lex-min (d, idx) within 16-lane group
#pragma unroll
  for (int off = 8; off >= 1; off >>= 1) {
    float od = __shfl_xor(d, off, 16);
    int oi = __shfl_xor(idx, off, 16);
    if (od < d || (od == d && oi < idx)) { d = od; idx = oi; }
  }
  if (idx == 0x7fffffff) idx = 0;  // defensive (can't happen: winner always emitted)
  if (sl == 0) out[(size_t)NZ + 1 + R] = (float)idx;

  // ---- fused outputs: wave loops its 4 rows; all 64 lanes per row ----
  double lsum = 0.0;
#pragma unroll
  for (int r = 0; r < 4; ++r) {
    int wi = __shfl(idx, r * 16, 64);
    size_t Rr = R0 + w * 4 + r;
    const float* cw = cb + (size_t)wi * DIM;
    float4v q = *(const float4v*)(cw + l * 4);
    float4v zv = *(const float4v*)&zs[w * 4 + r][l * 4];
    float4v o;
#pragma unroll
    for (int c = 0; c < 4; ++c) {
      float dq = __fsub_rn(q[c], zv[c]);
      o[c] = __fadd_rn(zv[c], dq);
      lsum += (double)__fmul_rn(dq, dq);
    }
    *(float4v*)(out + Rr * DIM + l * 4) = o;
  }

  // loss: wave-reduce then 1 atomic per block
#pragma unroll
  for (int off = 32; off; off >>= 1) lsum += __shfl_xor(lsum, off, 64);
  if (l == 0) lpart[w] = lsum;
  __syncthreads();
  if (tid == 0)
    atomicAdd(lacc, lpart[0] + lpart[1] + lpart[2] + lpart[3]);
}

__global__ void vq_finalize(const double* __restrict__ lacc, float* __restrict__ out) {
  double m = *lacc / (double)((size_t)N_ROWS * DIM);
  float mf = (float)m;
  out[NZ] = __fadd_rn(mf, __fmul_rn(0.25f, mf));
}

extern "C" void kernel_launch(void* const* d_in, const int* in_sizes, int n_in,
                              void* d_out, int out_size, void* d_ws, size_t ws_size,
                              hipStream_t stream) {
  const float* z = (const float*)d_in[0];
  const float* cb = (const float*)d_in[1];
  float* out = (float*)d_out;

  double* lacc = (double*)d_ws;
  int* cnt = (int*)((char*)d_ws + 256);
  unsigned short* cand = (unsigned short*)((char*)d_ws + 256 + N_ROWS * 4);
  short* chi = (short*)((char*)d_ws + (2u << 20));

  hipMemsetAsync(d_ws, 0, 256 + N_ROWS * 4, stream);
  hipLaunchKernelGGL(vq_conv, dim3(KCODES * DIM / 8 / 256), dim3(256), 0, stream, cb, chi);
  hipLaunchKernelGGL(vq_screen, dim3(N_ROWS / 64), dim3(256), 0, stream, z, chi, cnt, cand);
  hipLaunchKernelGGL(vq_recheck2, dim3(N_ROWS / 16), dim3(256), 0, stream, z, cb, cnt, cand, out, lacc);
  hipLaunchKernelGGL(vq_finalize, dim3(1), dim3(1), 0, stream, lacc, out);
}